// Round 1
// baseline (919.027 us; speedup 1.0000x reference)
//
#include <hip/hip_runtime.h>

#define G 4
#define NBATCH 8
#define HIN 128
#define HD 2324
#define NW 36864
#define NBIAS 64
#define NO 36928   // NW + NBIAS
#define GIN 64
#define GOUT 64
#define HIMG 64
#define WIMG 64
#define CIN 256

// K1: h[g][b][d] = relu(b1[g][d] + sum_i hyper[b][i] * W1[g][i][d])
__global__ __launch_bounds__(256) void k1_hyper_l1(
    const float* __restrict__ hyper, const float* __restrict__ W1,
    const float* __restrict__ b1, float* __restrict__ h) {
  int g = blockIdx.y;
  int d = blockIdx.x * 256 + threadIdx.x;
  if (d >= HD) return;
  const float* W1g = W1 + (size_t)g * HIN * HD + d;
  float bias = b1[g * HD + d];
  float acc[NBATCH];
#pragma unroll
  for (int b = 0; b < NBATCH; ++b) acc[b] = bias;
  for (int i = 0; i < HIN; ++i) {
    float wv = W1g[(size_t)i * HD];   // lane-coalesced
#pragma unroll
    for (int b = 0; b < NBATCH; ++b)
      acc[b] = fmaf(hyper[b * HIN + i], wv, acc[b]);  // uniform -> s_load
  }
#pragma unroll
  for (int b = 0; b < NBATCH; ++b)
    h[(size_t)(g * NBATCH + b) * HD + d] = fmaxf(acc[b], 0.0f);
}

// K2: gened[g][b][o] = b2[g][o] + sum_d h[g][b][d] * W2[g][d][o]
__global__ __launch_bounds__(256) void k2_hyper_l2(
    const float* __restrict__ h, const float* __restrict__ W2,
    const float* __restrict__ b2, float* __restrict__ gened) {
  int g = blockIdx.y;
  int o = blockIdx.x * 256 + threadIdx.x;
  if (o >= NO) return;
  const float* W2g = W2 + (size_t)g * HD * NO + o;
  const float* hg = h + (size_t)g * NBATCH * HD;
  float bias = b2[g * NO + o];
  float acc[NBATCH];
#pragma unroll
  for (int b = 0; b < NBATCH; ++b) acc[b] = bias;
#pragma unroll 4
  for (int d = 0; d < HD; ++d) {
    float wv = W2g[(size_t)d * NO];   // lane-coalesced, streams 1.37 GB
#pragma unroll
    for (int b = 0; b < NBATCH; ++b)
      acc[b] = fmaf(hg[b * HD + d], wv, acc[b]);  // uniform -> s_load
  }
#pragma unroll
  for (int b = 0; b < NBATCH; ++b)
    gened[(size_t)(g * NBATCH + b) * NO + o] = acc[b];
}

// K3: grouped dynamic 3x3 conv.
// block = (pixel tile 16x16, g, b); thread = 1 pixel; acc[64] = all group outputs
__global__ __launch_bounds__(256) void k3_conv(
    const float* __restrict__ image, const float* __restrict__ gened,
    float* __restrict__ out) {
  __shared__ float tile[18 * 18];
  int t = blockIdx.x;            // 0..15 -> 4x4 grid of 16x16 tiles
  int g = blockIdx.y;
  int b = blockIdx.z;
  int y0 = (t >> 2) * 16, x0 = (t & 3) * 16;
  int tid = threadIdx.x;
  int py = tid >> 4, px = tid & 15;
  int y = y0 + py, x = x0 + px;

  const float* gw = gened + (size_t)(g * NBATCH + b) * NO;  // weights+bias row
  float acc[GOUT];
#pragma unroll
  for (int o = 0; o < GOUT; ++o) acc[o] = gw[NW + o];  // bias (uniform s_load)

  for (int c = 0; c < GIN; ++c) {
    const float* imgc = image + ((size_t)b * CIN + g * GIN + c) * (HIMG * WIMG);
    __syncthreads();  // protect previous iteration's tile reads
    for (int i = tid; i < 18 * 18; i += 256) {
      int iy = i / 18, ix = i % 18;
      int gy = y0 - 1 + iy, gx = x0 - 1 + ix;
      float v = 0.0f;
      if (gy >= 0 && gy < HIMG && gx >= 0 && gx < WIMG) v = imgc[gy * WIMG + gx];
      tile[i] = v;
    }
    __syncthreads();
    float p[9];
#pragma unroll
    for (int ky = 0; ky < 3; ++ky)
#pragma unroll
      for (int kx = 0; kx < 3; ++kx)
        p[ky * 3 + kx] = tile[(py + ky) * 18 + (px + kx)];
    const float* wc = gw + c * 9;
#pragma unroll
    for (int o = 0; o < GOUT; ++o) {
      const float* w = wc + o * 576;   // uniform -> s_load, broadcast to wave
#pragma unroll
      for (int k = 0; k < 9; ++k)
        acc[o] = fmaf(p[k], w[k], acc[o]);
    }
  }
  float* outp = out + ((size_t)b * CIN + g * GOUT) * (HIMG * WIMG) + y * WIMG + x;
#pragma unroll
  for (int o = 0; o < GOUT; ++o)
    outp[(size_t)o * (HIMG * WIMG)] = acc[o];
}

extern "C" void kernel_launch(void* const* d_in, const int* in_sizes, int n_in,
                              void* d_out, int out_size, void* d_ws, size_t ws_size,
                              hipStream_t stream) {
  const float* image = (const float*)d_in[0];
  const float* hyper = (const float*)d_in[1];
  const float* W1    = (const float*)d_in[2];
  const float* b1    = (const float*)d_in[3];
  const float* W2    = (const float*)d_in[4];
  const float* b2    = (const float*)d_in[5];
  float* out = (float*)d_out;

  float* h     = (float*)d_ws;                      // G*B*HD   = 74368 f32
  float* gened = h + (size_t)G * NBATCH * HD;       // G*B*NO   = 1181696 f32

  k1_hyper_l1<<<dim3((HD + 255) / 256, G), 256, 0, stream>>>(hyper, W1, b1, h);
  k2_hyper_l2<<<dim3((NO + 255) / 256, G), 256, 0, stream>>>(h, W2, b2, gened);
  k3_conv<<<dim3(16, G, NBATCH), 256, 0, stream>>>(image, gened, out);
}

// Round 2
// 507.660 us; speedup vs baseline: 1.8103x; 1.8103x over previous
//
#include <hip/hip_runtime.h>

#define G 4
#define NBATCH 8
#define HIN 128
#define HD 2324
#define NW 36864
#define NO 36928   // NW + 64 biases
#define NO4 (NO / 4)        // 9232
#define GIN 64
#define GOUT 64
#define HIMG 64
#define WIMG 64
#define CIN 256
#define DSPLIT 8
#define DCHUNK 291          // ceil(2324/8)
#define OSPLIT 4            // k3: output channels per block = 16

// K1: h[g][b][d] = relu(b1[g][d] + sum_i hyper[b][i] * W1[g][i][d])
__global__ __launch_bounds__(256) void k1_hyper_l1(
    const float* __restrict__ hyper, const float* __restrict__ W1,
    const float* __restrict__ b1, float* __restrict__ h) {
  int g = blockIdx.y;
  int d = blockIdx.x * 256 + threadIdx.x;
  if (d >= HD) return;
  const float* W1g = W1 + (size_t)g * HIN * HD + d;
  float bias = b1[g * HD + d];
  float acc[NBATCH];
#pragma unroll
  for (int b = 0; b < NBATCH; ++b) acc[b] = bias;
  for (int i = 0; i < HIN; ++i) {
    float wv = W1g[(size_t)i * HD];
#pragma unroll
    for (int b = 0; b < NBATCH; ++b)
      acc[b] = fmaf(hyper[b * HIN + i], wv, acc[b]);
  }
#pragma unroll
  for (int b = 0; b < NBATCH; ++b)
    h[(size_t)(g * NBATCH + b) * HD + d] = fmaxf(acc[b], 0.0f);
}

// K2: partial[ds][g][b][o] = sum_{d in chunk ds} h[g][b][d] * W2[g][d][o]
// float4 loads of W2 (coalesced 1KiB/wave), split-K over DSPLIT chunks.
__global__ __launch_bounds__(256) void k2_hyper_l2(
    const float* __restrict__ h, const float* __restrict__ W2,
    float* __restrict__ partial) {
  int g = blockIdx.y, ds = blockIdx.z;
  int o4 = blockIdx.x * 256 + threadIdx.x;
  if (o4 >= NO4) return;
  const float4* W2g = (const float4*)(W2 + (size_t)g * HD * NO) + o4;
  const float* hg = h + (size_t)g * NBATCH * HD;
  int d0 = ds * DCHUNK;
  int d1 = d0 + DCHUNK; if (d1 > HD) d1 = HD;
  float4 acc[NBATCH];
#pragma unroll
  for (int b = 0; b < NBATCH; ++b) acc[b] = make_float4(0.f, 0.f, 0.f, 0.f);
#pragma unroll 2
  for (int d = d0; d < d1; ++d) {
    float4 wv = W2g[(size_t)d * NO4];         // streams W2, 16B/lane
#pragma unroll
    for (int b = 0; b < NBATCH; ++b) {
      float hv = hg[b * HD + d];              // uniform -> s_load
      acc[b].x = fmaf(hv, wv.x, acc[b].x);
      acc[b].y = fmaf(hv, wv.y, acc[b].y);
      acc[b].z = fmaf(hv, wv.z, acc[b].z);
      acc[b].w = fmaf(hv, wv.w, acc[b].w);
    }
  }
  float4* pout = (float4*)partial + (size_t)(ds * G + g) * NBATCH * NO4 + o4;
#pragma unroll
  for (int b = 0; b < NBATCH; ++b) pout[(size_t)b * NO4] = acc[b];
}

// K2r: gened[g][b][o] = b2[g][o] + sum_ds partial[ds][g][b][o]
__global__ __launch_bounds__(256) void k2_reduce(
    const float* __restrict__ partial, const float* __restrict__ b2,
    float* __restrict__ gened) {
  const int NF4 = G * NBATCH * NO4;           // 295424
  int q = blockIdx.x * 256 + threadIdx.x;
  if (q >= NF4) return;
  int gb = q / NO4;                           // 0..31
  int g = gb >> 3;
  int o4 = q - gb * NO4;
  float4 s = ((const float4*)(b2 + (size_t)g * NO))[o4];
  const float4* p = (const float4*)partial + q;
#pragma unroll
  for (int ds = 0; ds < DSPLIT; ++ds) {
    float4 v = p[(size_t)ds * NF4];
    s.x += v.x; s.y += v.y; s.z += v.z; s.w += v.w;
  }
  ((float4*)gened)[q] = s;
}

// K3: grouped dynamic 3x3 conv. block = (16x16 pixel tile, g, b*4+os);
// each block computes 16 output channels; LDS tile double-buffered.
__global__ __launch_bounds__(256) void k3_conv(
    const float* __restrict__ image, const float* __restrict__ gened,
    float* __restrict__ out) {
  __shared__ float tile[2][18 * 18];
  int t = blockIdx.x;
  int g = blockIdx.y;
  int bz = blockIdx.z;
  int b = bz >> 2, os = bz & 3;
  int y0 = (t >> 2) << 4, x0 = (t & 3) << 4;
  int tid = threadIdx.x;
  int py = tid >> 4, px = tid & 15;
  int obase = os * 16;

  const float* gw = gened + (size_t)(g * NBATCH + b) * NO;
  const float* imgb = image + ((size_t)b * CIN + g * GIN) * (HIMG * WIMG);

  float acc[16];
#pragma unroll
  for (int oo = 0; oo < 16; ++oo) acc[oo] = gw[NW + obase + oo];  // bias

  // stage channel 0
  for (int i = tid; i < 18 * 18; i += 256) {
    int iy = i / 18, ix = i % 18;
    int gy = y0 - 1 + iy, gx = x0 - 1 + ix;
    float v = 0.0f;
    if (gy >= 0 && gy < HIMG && gx >= 0 && gx < WIMG) v = imgb[gy * WIMG + gx];
    tile[0][i] = v;
  }
  __syncthreads();

  for (int c = 0; c < GIN; ++c) {
    int cur = c & 1;
    if (c + 1 < GIN) {                         // prefetch next channel
      const float* imgc = imgb + (size_t)(c + 1) * (HIMG * WIMG);
      for (int i = tid; i < 18 * 18; i += 256) {
        int iy = i / 18, ix = i % 18;
        int gy = y0 - 1 + iy, gx = x0 - 1 + ix;
        float v = 0.0f;
        if (gy >= 0 && gy < HIMG && gx >= 0 && gx < WIMG) v = imgc[gy * WIMG + gx];
        tile[cur ^ 1][i] = v;
      }
    }
    float p[9];
#pragma unroll
    for (int ky = 0; ky < 3; ++ky)
#pragma unroll
      for (int kx = 0; kx < 3; ++kx)
        p[ky * 3 + kx] = tile[cur][(py + ky) * 18 + (px + kx)];
#pragma unroll
    for (int oo = 0; oo < 16; ++oo) {
      const float* w = gw + (size_t)(obase + oo) * 576 + c * 9;  // uniform s_load
#pragma unroll
      for (int k = 0; k < 9; ++k)
        acc[oo] = fmaf(p[k], w[k], acc[oo]);
    }
    __syncthreads();
  }

  int y = y0 + py, x = x0 + px;
  float* outp = out + ((size_t)b * CIN + g * GOUT + obase) * (HIMG * WIMG)
              + y * WIMG + x;
#pragma unroll
  for (int oo = 0; oo < 16; ++oo)
    outp[(size_t)oo * (HIMG * WIMG)] = acc[oo];
}

extern "C" void kernel_launch(void* const* d_in, const int* in_sizes, int n_in,
                              void* d_out, int out_size, void* d_ws, size_t ws_size,
                              hipStream_t stream) {
  const float* image = (const float*)d_in[0];
  const float* hyper = (const float*)d_in[1];
  const float* W1    = (const float*)d_in[2];
  const float* b1    = (const float*)d_in[3];
  const float* W2    = (const float*)d_in[4];
  const float* b2    = (const float*)d_in[5];
  float* out = (float*)d_out;

  float* h       = (float*)d_ws;                           // 74368 f32
  float* gened   = h + (size_t)G * NBATCH * HD;            // 1181696 f32
  float* partial = gened + (size_t)G * NBATCH * NO;        // 9453568 f32

  k1_hyper_l1<<<dim3((HD + 255) / 256, G), 256, 0, stream>>>(hyper, W1, b1, h);
  k2_hyper_l2<<<dim3((NO4 + 255) / 256, G, DSPLIT), 256, 0, stream>>>(h, W2, partial);
  k2_reduce<<<dim3((G * NBATCH * NO4 + 255) / 256), 256, 0, stream>>>(partial, b2, gened);
  k3_conv<<<dim3(16, G, NBATCH * OSPLIT), 256, 0, stream>>>(image, gened, out);
}